// Round 15
// baseline (189.305 us; speedup 1.0000x reference)
//
#include <hip/hip_runtime.h>

// SetNetwork: per-request MLP (64->256->256) + ragged sum-pool + head.
// Round 15: R12 base + two surgical barrier-latency fixes:
//  (a) B1 counted-wait: after the first iteration, B1 = s_waitcnt vmcnt(2)
//      lgkmcnt(0) + sched_barrier(0) + s_barrier. The 2 allowed outstanding
//      VMEM ops are the part stores issued right before B1 (in-order vmcnt
//      retirement => the older DMAs are complete). Removes ~300-500 cyc/item
//      of store-drain exposure. sched_barrier(0) after the DMA issue pins
//      DMA-before-later-VMEM program order.
//  (b) SGPR metadata carry: worklist/n_req for item i+G prefetched one item
//      ahead, so the DMA at B2 issues with zero load latency.
// Everything else identical to R12/R14 (measured stable optimum).

typedef __bf16 bf16x8 __attribute__((ext_vector_type(8)));
typedef __bf16 bf16x4 __attribute__((ext_vector_type(4)));
typedef float f32x4 __attribute__((ext_vector_type(4)));

#define MFMA16(a, b, c) __builtin_amdgcn_mfma_f32_16x16x32_bf16((a), (b), (c), 0, 0, 0)

#define G_BLOCKS 512  // 2 blocks/CU x 256 CUs

// NT (non-temporal) cache policy: x_req is stream-once data.
#define ASYNC_COPY16_NT(gsrc, ldst)                                   \
  __builtin_amdgcn_global_load_lds(                                   \
      (__attribute__((address_space(1))) void*)(gsrc),                \
      (__attribute__((address_space(3))) void*)(ldst), 16, 0, 2)

// ---------------------------------------------------------------------------
// K1 (fused): blocks 0..319 convert+transpose weights to bf16 (coalesced
//             reads); block 320 prefix-scans n_req into a worklist + zbuf.
// ---------------------------------------------------------------------------
__global__ __launch_bounds__(256) void prep(const float* __restrict__ Win,
                                            const float* __restrict__ We1,
                                            const int* __restrict__ n_req,
                                            __bf16* __restrict__ WinT,
                                            __bf16* __restrict__ We1T,
                                            unsigned int* __restrict__ worklist,
                                            int* __restrict__ wl_count,
                                            float* __restrict__ zbuf) {
  if (blockIdx.x < 320) {
    int t = blockIdx.x * 256 + threadIdx.x;
    if (t < 16384) {
      int k = t >> 8, nn = t & 255;          // Win[k][nn], read coalesced
      WinT[nn * 64 + k] = (__bf16)Win[t];    // WinT[256][64]
    } else {
      int e = t - 16384;                      // 0..65535
      int k = e >> 8, nn = e & 255;          // We1[k][nn], read coalesced
      We1T[nn * 256 + k] = (__bf16)We1[e];   // We1T[256][256]
    }
    return;
  }
  // ---- zero the 4 KB zero-source buffer ----
  ((float4*)zbuf)[threadIdx.x] = make_float4(0.f, 0.f, 0.f, 0.f);
  // ---- worklist build: 256 threads x 8 batches each ----
  __shared__ int wsum[4];
  const int tid = threadIdx.x;
  const int base = tid * 8;
  int nt[8], s = 0;
#pragma unroll
  for (int j = 0; j < 8; ++j) {
    int n = n_req[base + j];
    nt[j] = (n + 63) >> 6;  // tiles for this batch (0..8)
    s += nt[j];
  }
  const int lane = tid & 63, wv = tid >> 6;
  int inc = s;
#pragma unroll
  for (int d = 1; d < 64; d <<= 1) {
    int u = __shfl_up(inc, d);
    if (lane >= d) inc += u;
  }
  if (lane == 63) wsum[wv] = inc;
  __syncthreads();
  int woff = 0;
  for (int w = 0; w < wv; ++w) woff += wsum[w];
  int off = woff + inc - s;  // exclusive prefix for this thread
#pragma unroll
  for (int j = 0; j < 8; ++j) {
    int b = base + j;
    for (int t = 0; t < nt[j]; ++t) worklist[off++] = (unsigned int)(b * 8 + t);
  }
  if (tid == 255) wl_count[0] = woff + inc;
}

// ---------------------------------------------------------------------------
// K2: persistent 512-thread blocks over worklist items.
// Wave wv (0..7) owns output cols [wv*32, wv*32+32).  Per item:
//   B1 (first: __syncthreads; rest: vmcnt(2)+lgkmcnt(0)+s_barrier)
//   -> layer1 MFMA from Af (inline fp32->bf16 cvt) -> H
//   -> B2 (__syncthreads) -> issue DMA(i+G) from SGPR-carried metadata
//   -> prefetch metadata(i+2G) -> layer2 MFMA -> colsum -> part store.
// Af chunk-swizzled: LDS chunk p of row r holds source chunk p^(r&15).
// ---------------------------------------------------------------------------
__global__ __launch_bounds__(512, 4) void mlp_pool(const float* __restrict__ x_req,
                                                   const int* __restrict__ n_req,
                                                   const __bf16* __restrict__ WinT,
                                                   const __bf16* __restrict__ We1T,
                                                   const unsigned int* __restrict__ worklist,
                                                   const int* __restrict__ wl_count,
                                                   const float* __restrict__ zbuf,
                                                   float* __restrict__ part) {
  __shared__ __align__(16) float Af[64 * 64];    // 16 KB, linear (swizzled data)
  __shared__ __align__(16) __bf16 H[64][264];    // 33 KB layer-1 out

  const int tid = threadIdx.x;
  const int wv = tid >> 6;     // wave id 0..7 -> col slice wv*32
  const int lane = tid & 63;
  const int llo = lane & 15;
  const int lhi = lane >> 4;
  const int c0 = wv * 32;

  const int count = wl_count[0];
  int i = blockIdx.x;
  if (i >= count) return;

  // Layer-1 B fragments (W_in^T slice), loaded once per block (16 VGPRs).
  bf16x8 bw1[2][2];
#pragma unroll
  for (int nf = 0; nf < 2; ++nf)
#pragma unroll
    for (int kk = 0; kk < 2; ++kk)
      bw1[nf][kk] = *(const bf16x8*)(WinT + (c0 + nf * 16 + llo) * 64 +
                                     kk * 32 + lhi * 8);

  // ---- prologue: stage item i into Af; prefetch item i+G metadata ----
  unsigned int cit = worklist[i];
  {
    int cb = (int)(cit >> 3), ct = (int)(cit & 7);
    int cv = min(64, n_req[cb] - ct * 64);
    const float* src = x_req + ((size_t)cb * 512 + (size_t)ct * 64) * 64;
#pragma unroll
    for (int s = 0; s < 2; ++s) {
      const int row = wv * 8 + s * 4 + lhi;
      const int gc = llo ^ (row & 15);  // source chunk (XOR swizzle)
      const float* g = (row < cv) ? (src + row * 64 + gc * 4) : (zbuf + llo * 4);
      ASYNC_COPY16_NT(g, Af + (wv * 8 + s * 4) * 64);
    }
  }
  unsigned int nit = 0u;
  int nv = 0;
  if (i + G_BLOCKS < count) {
    nit = worklist[i + G_BLOCKS];
    nv = min(64, n_req[nit >> 3] - (int)(nit & 7) * 64);
  }

  for (; i < count; i += G_BLOCKS) {
    // ---- B1: Af staged, H free. First iteration: full drain. After:
    //      counted wait — allow the 2 just-issued part stores to fly. ----
    if (i == (int)blockIdx.x) {
      __syncthreads();
    } else {
      asm volatile("s_waitcnt vmcnt(2) lgkmcnt(0)" ::: "memory");
      __builtin_amdgcn_sched_barrier(0);
      __builtin_amdgcn_s_barrier();
    }

    // ---- layer 1 (swapped operands): D[n][m]; A read fp32-swizzled ----
    f32x4 acc[4][2];
#pragma unroll
    for (int mi = 0; mi < 4; ++mi)
#pragma unroll
      for (int nf = 0; nf < 2; ++nf) acc[mi][nf] = (f32x4){0.f, 0.f, 0.f, 0.f};
#pragma unroll
    for (int kk = 0; kk < 2; ++kk)
#pragma unroll
      for (int mi = 0; mi < 4; ++mi) {
        const int row = mi * 16 + llo;
        const int cb = kk * 8 + lhi * 2;
        f32x4 lo = *(const f32x4*)(Af + row * 64 + ((cb) ^ llo) * 4);
        f32x4 hi = *(const f32x4*)(Af + row * 64 + ((cb + 1) ^ llo) * 4);
        bf16x8 a;
        a[0] = (__bf16)lo[0]; a[1] = (__bf16)lo[1];
        a[2] = (__bf16)lo[2]; a[3] = (__bf16)lo[3];
        a[4] = (__bf16)hi[0]; a[5] = (__bf16)hi[1];
        a[6] = (__bf16)hi[2]; a[7] = (__bf16)hi[3];
#pragma unroll
        for (int nf = 0; nf < 2; ++nf)
          acc[mi][nf] = MFMA16(bw1[nf][kk], a, acc[mi][nf]);
      }
#pragma unroll
    for (int mi = 0; mi < 4; ++mi)
#pragma unroll
      for (int nf = 0; nf < 2; ++nf) {
        bf16x4 hv;
#pragma unroll
        for (int r = 0; r < 4; ++r) hv[r] = (__bf16)fmaxf(acc[mi][nf][r], 0.f);
        *(bf16x4*)&H[mi * 16 + llo][c0 + nf * 16 + lhi * 4] = hv;
      }
    __syncthreads();  // B2: H ready; all waves done reading Af

    // ---- issue DMA for item i+G from carried metadata (zero load latency) ----
    const bool hn = (i + G_BLOCKS) < count;
    if (hn) {
      const float* nsrc = x_req + ((size_t)(nit >> 3) * 512 + (size_t)(nit & 7) * 64) * 64;
#pragma unroll
      for (int s = 0; s < 2; ++s) {
        const int row = wv * 8 + s * 4 + lhi;
        const int gc = llo ^ (row & 15);
        const float* g = (row < nv) ? (nsrc + row * 64 + gc * 4) : (zbuf + llo * 4);
        ASYNC_COPY16_NT(g, Af + (wv * 8 + s * 4) * 64);
      }
    }
    __builtin_amdgcn_sched_barrier(0);  // pin: DMAs precede all later VMEM

    // ---- prefetch metadata for item i+2G (consumed next iteration) ----
    unsigned int nit2 = 0u;
    int nv2 = 0;
    if (i + 2 * G_BLOCKS < count) {
      nit2 = worklist[i + 2 * G_BLOCKS];
      nv2 = min(64, n_req[nit2 >> 3] - (int)(nit2 & 7) * 64);
    }

    // ---- layer 2: [64x256] @ [256x(2x16)], relu, column sums (acc reused) ----
#pragma unroll
    for (int mi = 0; mi < 4; ++mi)
#pragma unroll
      for (int nf = 0; nf < 2; ++nf) acc[mi][nf] = (f32x4){0.f, 0.f, 0.f, 0.f};
#pragma unroll
    for (int kk = 0; kk < 8; ++kk) {
      bf16x8 a2[4];
#pragma unroll
      for (int mi = 0; mi < 4; ++mi)
        a2[mi] = *(const bf16x8*)&H[mi * 16 + llo][kk * 32 + lhi * 8];
#pragma unroll
      for (int nf = 0; nf < 2; ++nf) {
        bf16x8 bf_ = *(const bf16x8*)(We1T +
                        (size_t)(c0 + nf * 16 + llo) * 256 +
                        kk * 32 + lhi * 8);
#pragma unroll
        for (int mi = 0; mi < 4; ++mi)
          acc[mi][nf] = MFMA16(a2[mi], bf_, acc[mi][nf]);
      }
    }
    float colsum[2] = {0.f, 0.f};
#pragma unroll
    for (int mi = 0; mi < 4; ++mi)
#pragma unroll
      for (int nf = 0; nf < 2; ++nf)
#pragma unroll
        for (int r = 0; r < 4; ++r)
          colsum[nf] += fmaxf(acc[mi][nf][r], 0.f);

    // reduce across lane-groups; write this item's partial pooled slice
    float* outp = part + (size_t)cit * 256;
#pragma unroll
    for (int nf = 0; nf < 2; ++nf) {
      float s = colsum[nf];
      s += __shfl_xor(s, 16);
      s += __shfl_xor(s, 32);
      if (lane < 16) outp[c0 + nf * 16 + lane] = s;
    }

    cit = nit;
    nit = nit2;
    nv = nv2;
  }
}

// ---------------------------------------------------------------------------
// K3: head.  pooled = sum_{t<ceil(n/64)} part[b*8+t]; req_embed = relu(pooled
// @ W_e2); x = [x_inst, req_embed]; h = relu(x @ W_c + b_c); out = h@W_o+b_o.
// 4 batch rows per block, 512 blocks x 256 threads (2 blocks/CU), fp32.
// ---------------------------------------------------------------------------
__global__ __launch_bounds__(256) void head_kernel(const float* __restrict__ x_inst,
                                                   const float* __restrict__ part,
                                                   const int* __restrict__ n_req,
                                                   const float* __restrict__ We2,
                                                   const float* __restrict__ Wc,
                                                   const float* __restrict__ bc,
                                                   const float* __restrict__ Wo,
                                                   const float* __restrict__ bo,
                                                   float* __restrict__ out) {
  __shared__ float P[4][256];
  __shared__ float XC[4][192];
  __shared__ float RED[4][4];
  const int tid = threadIdx.x;
  const int r0 = blockIdx.x * 4;

  // stage pooled rows (4x256) = sum of valid partials; x_inst -> XC[:,0:64]
  {
    int row = tid >> 6, c4 = tid & 63;
    int ntiles = (n_req[r0 + row] + 63) >> 6;
    float4 s = make_float4(0.f, 0.f, 0.f, 0.f);
    for (int tt = 0; tt < ntiles; ++tt) {
      float4 p = ((const float4*)(part + ((size_t)(r0 + row) * 8 + tt) * 256))[c4];
      s.x += p.x; s.y += p.y; s.z += p.z; s.w += p.w;
    }
    *(float4*)&P[row][c4 * 4] = s;
  }
  if (tid < 64) {
    int row = tid >> 4, c4 = tid & 15;
    float4 w = ((const float4*)(x_inst + (size_t)(r0 + row) * 64))[c4];
    *(float4*)&XC[row][c4 * 4] = w;
  }
  __syncthreads();

  // req_embed: 128 cols; threads split {row-half rh (2 rows each), col j}
  {
    const int rh = tid >> 7, j = tid & 127;
    float acc[2] = {0.f, 0.f};
    for (int k4 = 0; k4 < 64; ++k4) {
      float w0 = We2[(k4 * 4 + 0) * 128 + j];
      float w1 = We2[(k4 * 4 + 1) * 128 + j];
      float w2 = We2[(k4 * 4 + 2) * 128 + j];
      float w3 = We2[(k4 * 4 + 3) * 128 + j];
#pragma unroll
      for (int rr = 0; rr < 2; ++rr) {
        float4 pv = *(const float4*)&P[rh * 2 + rr][k4 * 4];
        acc[rr] += pv.x * w0 + pv.y * w1 + pv.z * w2 + pv.w * w3;
      }
    }
#pragma unroll
    for (int rr = 0; rr < 2; ++rr)
      XC[rh * 2 + rr][64 + j] = fmaxf(acc[rr], 0.f);
  }
  __syncthreads();

  // hidden (192->512) + output dot, 2 cols per thread
  float pr[4] = {0.f, 0.f, 0.f, 0.f};
#pragma unroll
  for (int jj = 0; jj < 2; ++jj) {
    const int j = tid + jj * 256;
    float acc[4] = {0.f, 0.f, 0.f, 0.f};
    for (int k4 = 0; k4 < 48; ++k4) {
      float w0 = Wc[(k4 * 4 + 0) * 512 + j];
      float w1 = Wc[(k4 * 4 + 1) * 512 + j];
      float w2 = Wc[(k4 * 4 + 2) * 512 + j];
      float w3 = Wc[(k4 * 4 + 3) * 512 + j];
#pragma unroll
      for (int r = 0; r < 4; ++r) {
        float4 xv = *(const float4*)&XC[r][k4 * 4];
        acc[r] += xv.x * w0 + xv.y * w1 + xv.z * w2 + xv.w * w3;
      }
    }
    const float bcv = bc[j], wov = Wo[j];
#pragma unroll
    for (int r = 0; r < 4; ++r)
      pr[r] += fmaxf(acc[r] + bcv, 0.f) * wov;
  }
  // block reduction of pr[4] over 256 threads
#pragma unroll
  for (int r = 0; r < 4; ++r) {
    pr[r] += __shfl_xor(pr[r], 1);
    pr[r] += __shfl_xor(pr[r], 2);
    pr[r] += __shfl_xor(pr[r], 4);
    pr[r] += __shfl_xor(pr[r], 8);
    pr[r] += __shfl_xor(pr[r], 16);
    pr[r] += __shfl_xor(pr[r], 32);
  }
  const int wvv = tid >> 6, lane = tid & 63;
  if (lane == 0) {
#pragma unroll
    for (int r = 0; r < 4; ++r) RED[wvv][r] = pr[r];
  }
  __syncthreads();
  if (tid < 4)
    out[r0 + tid] = RED[0][tid] + RED[1][tid] + RED[2][tid] + RED[3][tid] + bo[0];
}

// ---------------------------------------------------------------------------
extern "C" void kernel_launch(void* const* d_in, const int* in_sizes, int n_in,
                              void* d_out, int out_size, void* d_ws, size_t ws_size,
                              hipStream_t stream) {
  const float* x_inst = (const float*)d_in[0];
  const float* x_req  = (const float*)d_in[1];
  const int*   n_req  = (const int*)d_in[2];
  const float* W_in   = (const float*)d_in[3];
  const float* W_e1   = (const float*)d_in[4];
  const float* W_e2   = (const float*)d_in[5];
  const float* W_c    = (const float*)d_in[6];
  const float* b_c    = (const float*)d_in[7];
  const float* W_o    = (const float*)d_in[8];
  const float* b_o    = (const float*)d_in[9];
  float* out = (float*)d_out;

  char* ws = (char*)d_ws;
  const size_t PART_BYTES = (size_t)2048 * 8 * 256 * 4;        // 16.78 MB
  float*        partbuf  = (float*)ws;
  __bf16*       WinT     = (__bf16*)(ws + PART_BYTES);                 // 32 KiB
  __bf16*       We1T     = (__bf16*)(ws + PART_BYTES + (32 << 10));    // 128 KiB
  unsigned int* worklist = (unsigned int*)(ws + PART_BYTES + (160 << 10));  // 64 KiB
  int*          wl_count = (int*)(ws + PART_BYTES + (224 << 10));
  float*        zbuf     = (float*)(ws + PART_BYTES + (228 << 10));    // 4 KiB zeros

  prep<<<321, 256, 0, stream>>>(W_in, W_e1, n_req, WinT, We1T, worklist,
                                wl_count, zbuf);
  mlp_pool<<<G_BLOCKS, 512, 0, stream>>>(x_req, n_req, WinT, We1T, worklist,
                                         wl_count, zbuf, partbuf);
  head_kernel<<<512, 256, 0, stream>>>(x_inst, partbuf, n_req, W_e2, W_c, b_c,
                                       W_o, b_o, out);
}

// Round 16
// 177.350 us; speedup vs baseline: 1.0674x; 1.0674x over previous
//
#include <hip/hip_runtime.h>

// SetNetwork: per-request MLP (64->256->256) + ragged sum-pool + head.
// Round 16: RESTORE R12/R14 verbatim — the measured optimum (177.6-180.1 us).
// R15's counted-wait B1 + SGPR metadata carry regressed mlp 156->173 us
// (same signature as R10: sched_barrier(0) order-pinning + carried live
// ranges defeat hipcc's scheduler — guide Common-mistake pattern m141).
// Full measured-negative list for this loop (do not retry):
//   3 blocks/CU (R3/R11), cap128+wide-acc (R5), convert-once (R9),
//   dbuf+lean-B2 (R10), 2D wave tile (R13), counted-wait+carry (R15).
// Session: fp32 baseline 282 us -> this kernel ~178 us.

typedef __bf16 bf16x8 __attribute__((ext_vector_type(8)));
typedef __bf16 bf16x4 __attribute__((ext_vector_type(4)));
typedef float f32x4 __attribute__((ext_vector_type(4)));

#define MFMA16(a, b, c) __builtin_amdgcn_mfma_f32_16x16x32_bf16((a), (b), (c), 0, 0, 0)

#define G_BLOCKS 512  // 2 blocks/CU x 256 CUs

// NT (non-temporal) cache policy: x_req is stream-once data.
#define ASYNC_COPY16_NT(gsrc, ldst)                                   \
  __builtin_amdgcn_global_load_lds(                                   \
      (__attribute__((address_space(1))) void*)(gsrc),                \
      (__attribute__((address_space(3))) void*)(ldst), 16, 0, 2)

// ---------------------------------------------------------------------------
// K1 (fused): blocks 0..319 convert+transpose weights to bf16 (coalesced
//             reads); block 320 prefix-scans n_req into a worklist + zbuf.
// ---------------------------------------------------------------------------
__global__ __launch_bounds__(256) void prep(const float* __restrict__ Win,
                                            const float* __restrict__ We1,
                                            const int* __restrict__ n_req,
                                            __bf16* __restrict__ WinT,
                                            __bf16* __restrict__ We1T,
                                            unsigned int* __restrict__ worklist,
                                            int* __restrict__ wl_count,
                                            float* __restrict__ zbuf) {
  if (blockIdx.x < 320) {
    int t = blockIdx.x * 256 + threadIdx.x;
    if (t < 16384) {
      int k = t >> 8, nn = t & 255;          // Win[k][nn], read coalesced
      WinT[nn * 64 + k] = (__bf16)Win[t];    // WinT[256][64]
    } else {
      int e = t - 16384;                      // 0..65535
      int k = e >> 8, nn = e & 255;          // We1[k][nn], read coalesced
      We1T[nn * 256 + k] = (__bf16)We1[e];   // We1T[256][256]
    }
    return;
  }
  // ---- zero the 4 KB zero-source buffer ----
  ((float4*)zbuf)[threadIdx.x] = make_float4(0.f, 0.f, 0.f, 0.f);
  // ---- worklist build: 256 threads x 8 batches each ----
  __shared__ int wsum[4];
  const int tid = threadIdx.x;
  const int base = tid * 8;
  int nt[8], s = 0;
#pragma unroll
  for (int j = 0; j < 8; ++j) {
    int n = n_req[base + j];
    nt[j] = (n + 63) >> 6;  // tiles for this batch (0..8)
    s += nt[j];
  }
  const int lane = tid & 63, wv = tid >> 6;
  int inc = s;
#pragma unroll
  for (int d = 1; d < 64; d <<= 1) {
    int u = __shfl_up(inc, d);
    if (lane >= d) inc += u;
  }
  if (lane == 63) wsum[wv] = inc;
  __syncthreads();
  int woff = 0;
  for (int w = 0; w < wv; ++w) woff += wsum[w];
  int off = woff + inc - s;  // exclusive prefix for this thread
#pragma unroll
  for (int j = 0; j < 8; ++j) {
    int b = base + j;
    for (int t = 0; t < nt[j]; ++t) worklist[off++] = (unsigned int)(b * 8 + t);
  }
  if (tid == 255) wl_count[0] = woff + inc;
}

// ---------------------------------------------------------------------------
// K2: persistent 512-thread blocks over worklist items.
// Wave wv (0..7) owns output cols [wv*32, wv*32+32).  A: single fp32 [64][64]
// LDS tile via global_load_lds (NT), source chunk XOR-swizzled by (row&15),
// LDS dest linear.  Staging for item i+1 issues right after B2 (under layer2
// MFMAs); B1's vmcnt(0)+barrier completes it.
// ---------------------------------------------------------------------------
__global__ __launch_bounds__(512, 4) void mlp_pool(const float* __restrict__ x_req,
                                                   const int* __restrict__ n_req,
                                                   const __bf16* __restrict__ WinT,
                                                   const __bf16* __restrict__ We1T,
                                                   const unsigned int* __restrict__ worklist,
                                                   const int* __restrict__ wl_count,
                                                   const float* __restrict__ zbuf,
                                                   float* __restrict__ part) {
  __shared__ __align__(16) float Af[64 * 64];    // 16 KB, linear (swizzled data)
  __shared__ __align__(16) __bf16 H[64][264];    // 33 KB layer-1 out

  const int tid = threadIdx.x;
  const int wv = tid >> 6;     // wave id 0..7 -> col slice wv*32
  const int lane = tid & 63;
  const int llo = lane & 15;
  const int lhi = lane >> 4;
  const int c0 = wv * 32;

  const int count = wl_count[0];
  int i = blockIdx.x;
  if (i >= count) return;

  // Layer-1 B fragments (W_in^T slice), loaded once per block (16 VGPRs).
  bf16x8 bw1[2][2];
#pragma unroll
  for (int nf = 0; nf < 2; ++nf)
#pragma unroll
    for (int kk = 0; kk < 2; ++kk)
      bw1[nf][kk] = *(const bf16x8*)(WinT + (c0 + nf * 16 + llo) * 64 +
                                     kk * 32 + lhi * 8);

  // ---- prologue: stage item i into Af ----
  unsigned int cit = worklist[i];
  {
    int cb = (int)(cit >> 3), ct = (int)(cit & 7);
    int cv = min(64, n_req[cb] - ct * 64);
    const float* src = x_req + ((size_t)cb * 512 + (size_t)ct * 64) * 64;
#pragma unroll
    for (int s = 0; s < 2; ++s) {
      const int row = wv * 8 + s * 4 + lhi;
      const int gc = llo ^ (row & 15);  // source chunk (XOR swizzle)
      const float* g = (row < cv) ? (src + row * 64 + gc * 4) : (zbuf + llo * 4);
      ASYNC_COPY16_NT(g, Af + (wv * 8 + s * 4) * 64);
    }
  }

  for (; i < count; i += G_BLOCKS) {
    __syncthreads();  // B1: vmcnt drained -> Af fully staged; H free

    // ---- layer 1 (swapped operands): D[n][m]; A read fp32-swizzled ----
    f32x4 acc[4][2];
#pragma unroll
    for (int mi = 0; mi < 4; ++mi)
#pragma unroll
      for (int nf = 0; nf < 2; ++nf) acc[mi][nf] = (f32x4){0.f, 0.f, 0.f, 0.f};
#pragma unroll
    for (int kk = 0; kk < 2; ++kk)
#pragma unroll
      for (int mi = 0; mi < 4; ++mi) {
        const int row = mi * 16 + llo;
        const int cb = kk * 8 + lhi * 2;
        f32x4 lo = *(const f32x4*)(Af + row * 64 + ((cb) ^ llo) * 4);
        f32x4 hi = *(const f32x4*)(Af + row * 64 + ((cb + 1) ^ llo) * 4);
        bf16x8 a;
        a[0] = (__bf16)lo[0]; a[1] = (__bf16)lo[1];
        a[2] = (__bf16)lo[2]; a[3] = (__bf16)lo[3];
        a[4] = (__bf16)hi[0]; a[5] = (__bf16)hi[1];
        a[6] = (__bf16)hi[2]; a[7] = (__bf16)hi[3];
#pragma unroll
        for (int nf = 0; nf < 2; ++nf)
          acc[mi][nf] = MFMA16(bw1[nf][kk], a, acc[mi][nf]);
      }
#pragma unroll
    for (int mi = 0; mi < 4; ++mi)
#pragma unroll
      for (int nf = 0; nf < 2; ++nf) {
        bf16x4 hv;
#pragma unroll
        for (int r = 0; r < 4; ++r) hv[r] = (__bf16)fmaxf(acc[mi][nf][r], 0.f);
        *(bf16x4*)&H[mi * 16 + llo][c0 + nf * 16 + lhi * 4] = hv;
      }
    __syncthreads();  // B2: H ready; all waves done reading Af

    // ---- next-item info + async staging issue (hides under layer2) ----
    const int inext = i + G_BLOCKS;
    const bool hn = inext < count;
    unsigned int nit = 0u;
    if (hn) {
      nit = worklist[inext];
      int nb = (int)(nit >> 3), ntl = (int)(nit & 7);
      int nv = min(64, n_req[nb] - ntl * 64);
      const float* nsrc = x_req + ((size_t)nb * 512 + (size_t)ntl * 64) * 64;
#pragma unroll
      for (int s = 0; s < 2; ++s) {
        const int row = wv * 8 + s * 4 + lhi;
        const int gc = llo ^ (row & 15);
        const float* g = (row < nv) ? (nsrc + row * 64 + gc * 4) : (zbuf + llo * 4);
        ASYNC_COPY16_NT(g, Af + (wv * 8 + s * 4) * 64);
      }
    }

    // ---- layer 2: [64x256] @ [256x(2x16)], relu, column sums (acc reused) ----
#pragma unroll
    for (int mi = 0; mi < 4; ++mi)
#pragma unroll
      for (int nf = 0; nf < 2; ++nf) acc[mi][nf] = (f32x4){0.f, 0.f, 0.f, 0.f};
#pragma unroll
    for (int kk = 0; kk < 8; ++kk) {
      bf16x8 a2[4];
#pragma unroll
      for (int mi = 0; mi < 4; ++mi)
        a2[mi] = *(const bf16x8*)&H[mi * 16 + llo][kk * 32 + lhi * 8];
#pragma unroll
      for (int nf = 0; nf < 2; ++nf) {
        bf16x8 bf_ = *(const bf16x8*)(We1T +
                        (size_t)(c0 + nf * 16 + llo) * 256 +
                        kk * 32 + lhi * 8);
#pragma unroll
        for (int mi = 0; mi < 4; ++mi)
          acc[mi][nf] = MFMA16(a2[mi], bf_, acc[mi][nf]);
      }
    }
    float colsum[2] = {0.f, 0.f};
#pragma unroll
    for (int mi = 0; mi < 4; ++mi)
#pragma unroll
      for (int nf = 0; nf < 2; ++nf)
#pragma unroll
        for (int r = 0; r < 4; ++r)
          colsum[nf] += fmaxf(acc[mi][nf][r], 0.f);

    // reduce across lane-groups; write this item's partial pooled slice
    float* outp = part + (size_t)cit * 256;
#pragma unroll
    for (int nf = 0; nf < 2; ++nf) {
      float s = colsum[nf];
      s += __shfl_xor(s, 16);
      s += __shfl_xor(s, 32);
      if (lane < 16) outp[c0 + nf * 16 + lane] = s;
    }

    cit = nit;
  }
}

// ---------------------------------------------------------------------------
// K3: head.  pooled = sum_{t<ceil(n/64)} part[b*8+t]; req_embed = relu(pooled
// @ W_e2); x = [x_inst, req_embed]; h = relu(x @ W_c + b_c); out = h@W_o+b_o.
// 4 batch rows per block, 512 blocks x 256 threads (2 blocks/CU), fp32.
// ---------------------------------------------------------------------------
__global__ __launch_bounds__(256) void head_kernel(const float* __restrict__ x_inst,
                                                   const float* __restrict__ part,
                                                   const int* __restrict__ n_req,
                                                   const float* __restrict__ We2,
                                                   const float* __restrict__ Wc,
                                                   const float* __restrict__ bc,
                                                   const float* __restrict__ Wo,
                                                   const float* __restrict__ bo,
                                                   float* __restrict__ out) {
  __shared__ float P[4][256];
  __shared__ float XC[4][192];
  __shared__ float RED[4][4];
  const int tid = threadIdx.x;
  const int r0 = blockIdx.x * 4;

  // stage pooled rows (4x256) = sum of valid partials; x_inst -> XC[:,0:64]
  {
    int row = tid >> 6, c4 = tid & 63;
    int ntiles = (n_req[r0 + row] + 63) >> 6;
    float4 s = make_float4(0.f, 0.f, 0.f, 0.f);
    for (int tt = 0; tt < ntiles; ++tt) {
      float4 p = ((const float4*)(part + ((size_t)(r0 + row) * 8 + tt) * 256))[c4];
      s.x += p.x; s.y += p.y; s.z += p.z; s.w += p.w;
    }
    *(float4*)&P[row][c4 * 4] = s;
  }
  if (tid < 64) {
    int row = tid >> 4, c4 = tid & 15;
    float4 w = ((const float4*)(x_inst + (size_t)(r0 + row) * 64))[c4];
    *(float4*)&XC[row][c4 * 4] = w;
  }
  __syncthreads();

  // req_embed: 128 cols; threads split {row-half rh (2 rows each), col j}
  {
    const int rh = tid >> 7, j = tid & 127;
    float acc[2] = {0.f, 0.f};
    for (int k4 = 0; k4 < 64; ++k4) {
      float w0 = We2[(k4 * 4 + 0) * 128 + j];
      float w1 = We2[(k4 * 4 + 1) * 128 + j];
      float w2 = We2[(k4 * 4 + 2) * 128 + j];
      float w3 = We2[(k4 * 4 + 3) * 128 + j];
#pragma unroll
      for (int rr = 0; rr < 2; ++rr) {
        float4 pv = *(const float4*)&P[rh * 2 + rr][k4 * 4];
        acc[rr] += pv.x * w0 + pv.y * w1 + pv.z * w2 + pv.w * w3;
      }
    }
#pragma unroll
    for (int rr = 0; rr < 2; ++rr)
      XC[rh * 2 + rr][64 + j] = fmaxf(acc[rr], 0.f);
  }
  __syncthreads();

  // hidden (192->512) + output dot, 2 cols per thread
  float pr[4] = {0.f, 0.f, 0.f, 0.f};
#pragma unroll
  for (int jj = 0; jj < 2; ++jj) {
    const int j = tid + jj * 256;
    float acc[4] = {0.f, 0.f, 0.f, 0.f};
    for (int k4 = 0; k4 < 48; ++k4) {
      float w0 = Wc[(k4 * 4 + 0) * 512 + j];
      float w1 = Wc[(k4 * 4 + 1) * 512 + j];
      float w2 = Wc[(k4 * 4 + 2) * 512 + j];
      float w3 = Wc[(k4 * 4 + 3) * 512 + j];
#pragma unroll
      for (int r = 0; r < 4; ++r) {
        float4 xv = *(const float4*)&XC[r][k4 * 4];
        acc[r] += xv.x * w0 + xv.y * w1 + xv.z * w2 + xv.w * w3;
      }
    }
    const float bcv = bc[j], wov = Wo[j];
#pragma unroll
    for (int r = 0; r < 4; ++r)
      pr[r] += fmaxf(acc[r] + bcv, 0.f) * wov;
  }
  // block reduction of pr[4] over 256 threads
#pragma unroll
  for (int r = 0; r < 4; ++r) {
    pr[r] += __shfl_xor(pr[r], 1);
    pr[r] += __shfl_xor(pr[r], 2);
    pr[r] += __shfl_xor(pr[r], 4);
    pr[r] += __shfl_xor(pr[r], 8);
    pr[r] += __shfl_xor(pr[r], 16);
    pr[r] += __shfl_xor(pr[r], 32);
  }
  const int wvv = tid >> 6, lane = tid & 63;
  if (lane == 0) {
#pragma unroll
    for (int r = 0; r < 4; ++r) RED[wvv][r] = pr[r];
  }
  __syncthreads();
  if (tid < 4)
    out[r0 + tid] = RED[0][tid] + RED[1][tid] + RED[2][tid] + RED[3][tid] + bo[0];
}

// ---------------------------------------------------------------------------
extern "C" void kernel_launch(void* const* d_in, const int* in_sizes, int n_in,
                              void* d_out, int out_size, void* d_ws, size_t ws_size,
                              hipStream_t stream) {
  const float* x_inst = (const float*)d_in[0];
  const float* x_req  = (const float*)d_in[1];
  const int*   n_req  = (const int*)d_in[2];
  const float* W_in   = (const float*)d_in[3];
  const float* W_e1   = (const float*)d_in[4];
  const float* W_e2   = (const float*)d_in[5];
  const float* W_c    = (const float*)d_in[6];
  const float* b_c    = (const float*)d_in[7];
  const float* W_o    = (const float*)d_in[8];
  const float* b_o    = (const float*)d_in[9];
  float* out = (float*)d_out;

  char* ws = (char*)d_ws;
  const size_t PART_BYTES = (size_t)2048 * 8 * 256 * 4;        // 16.78 MB
  float*        partbuf  = (float*)ws;
  __bf16*       WinT     = (__bf16*)(ws + PART_BYTES);                 // 32 KiB
  __bf16*       We1T     = (__bf16*)(ws + PART_BYTES + (32 << 10));    // 128 KiB
  unsigned int* worklist = (unsigned int*)(ws + PART_BYTES + (160 << 10));  // 64 KiB
  int*          wl_count = (int*)(ws + PART_BYTES + (224 << 10));
  float*        zbuf     = (float*)(ws + PART_BYTES + (228 << 10));    // 4 KiB zeros

  prep<<<321, 256, 0, stream>>>(W_in, W_e1, n_req, WinT, We1T, worklist,
                                wl_count, zbuf);
  mlp_pool<<<G_BLOCKS, 512, 0, stream>>>(x_req, n_req, WinT, We1T, worklist,
                                         wl_count, zbuf, partbuf);
  head_kernel<<<512, 256, 0, stream>>>(x_inst, partbuf, n_req, W_e2, W_c, b_c,
                                       W_o, b_o, out);
}